// Round 5
// baseline (196.472 us; speedup 1.0000x reference)
//
#include <hip/hip_runtime.h>
#include <math.h>

// SparseExpertCountingNetwork: N=131072 rows, H=2048, E=4 experts.
// out[n] = sum_e softmax(hist[n]@W.T + b + gumbel(u[n]))_e * expert_e(hist[n])
// experts = [sum, max/(sum+1e-6), count(!=0), count(adjacent !=)]
//
// HBM-bound (1.074 GB hist stream). R5 = R4 with ONE change: plain global
// loads instead of __builtin_nontemporal_load (A/B test: does the nt cache
// policy throttle read-stream BW? R4 measured 5.94 TB/s vs 6.45 fill).
//  - one wave per row, W register-resident (128 VGPRs), 2-row ping-pong
//  - wave reductions via DPP row_shr/row_bcast (VALU-only, result in lane 63)
//  - pattern-count boundary via DPP wave_shr:1 + v_readlane carry (VALU-only)
//  - ZERO LDS/DS instructions: pure VMEM + VALU

#define HDIM 2048
#define NITER 8  // HDIM / (64 lanes * 4 floats)

typedef float f32x4 __attribute__((ext_vector_type(4)));

// DPP full-wave reductions (VALU-only). After row_shr:1/2/4/8 + row_bcast:15
// + row_bcast:31, lane 63 holds the 64-lane result. (HW-validated R3/R4.)
#define DPP_ADD(x, ctrl)                                                     \
  (x) += __int_as_float(__builtin_amdgcn_update_dpp(                         \
      0, __float_as_int(x), (ctrl), 0xF, 0xF, false))
#define DPP_MAX(x, ctrl)                                                     \
  do {                                                                       \
    float _t = __int_as_float(__builtin_amdgcn_update_dpp(                   \
        __float_as_int(x), __float_as_int(x), (ctrl), 0xF, 0xF, false));     \
    (x) = fmaxf((x), _t);                                                    \
  } while (0)

__device__ __forceinline__ float wave_sum63(float x) {
  DPP_ADD(x, 0x111); DPP_ADD(x, 0x112); DPP_ADD(x, 0x114); DPP_ADD(x, 0x118);
  DPP_ADD(x, 0x142); DPP_ADD(x, 0x143);
  return x;  // valid in lane 63
}
__device__ __forceinline__ float wave_max63(float x) {
  DPP_MAX(x, 0x111); DPP_MAX(x, 0x112); DPP_MAX(x, 0x114); DPP_MAX(x, 0x118);
  DPP_MAX(x, 0x142); DPP_MAX(x, 0x143);
  return x;  // valid in lane 63
}

__global__ __launch_bounds__(256, 2) void moe_fused_kernel(
    const float* __restrict__ hist, const float* __restrict__ W,
    const float* __restrict__ bias, const float* __restrict__ gu,
    float* __restrict__ out, int N)
{
    const int lane = threadIdx.x & 63;
    const int wid  = threadIdx.x >> 6;
    const int gw   = blockIdx.x * 4 + wid;      // global wave id
    const int GW   = gridDim.x * 4;             // total waves
    const int cbase = 4 * lane;

    // W fragments in registers: w{e}[j] = W[e][256*j + 4*lane .. +3]
    f32x4 w0[NITER], w1[NITER], w2[NITER], w3[NITER];
#pragma unroll
    for (int j = 0; j < NITER; ++j) {
        int c = 256 * j + cbase;
        w0[j] = *(const f32x4*)(W + 0 * HDIM + c);
        w1[j] = *(const f32x4*)(W + 1 * HDIM + c);
        w2[j] = *(const f32x4*)(W + 2 * HDIM + c);
        w3[j] = *(const f32x4*)(W + 3 * HDIM + c);
    }
    const float b0 = bias[0], b1 = bias[1], b2 = bias[2], b3 = bias[3];

    // ---- row loader (plain loads; NT hint removed this round) ----
    auto loadrow = [&](int row, f32x4* h, f32x4& u) {
        const float* hr = hist + (size_t)row * HDIM;
#pragma unroll
        for (int j = 0; j < NITER; ++j)
            h[j] = *(const f32x4*)(hr + 256 * j + cbase);
        u = *(const f32x4*)(gu + (size_t)row * 4);
    };

    // ---- per-row compute + store (no DS ops anywhere) ----
    auto compute = [&](int row, const f32x4* h, f32x4 u4) {
        float d0 = 0.f, d1 = 0.f, d2 = 0.f, d3 = 0.f;
        float tot = 0.f, mx = -3.4e38f, cnt = 0.f;  // cnt = uq*4096 + pc (exact)

#pragma unroll
        for (int j = 0; j < NITER; ++j) {
            f32x4 v = h[j];
            d0 += v.x * w0[j].x + v.y * w0[j].y + v.z * w0[j].z + v.w * w0[j].w;
            d1 += v.x * w1[j].x + v.y * w1[j].y + v.z * w1[j].z + v.w * w1[j].w;
            d2 += v.x * w2[j].x + v.y * w2[j].y + v.z * w2[j].z + v.w * w2[j].w;
            d3 += v.x * w3[j].x + v.y * w3[j].y + v.z * w3[j].z + v.w * w3[j].w;
            tot += (v.x + v.y) + (v.z + v.w);
            mx = fmaxf(mx, fmaxf(fmaxf(v.x, v.y), fmaxf(v.z, v.w)));
            cnt += 4096.f * ((v.x != 0.f ? 1.f : 0.f) + (v.y != 0.f ? 1.f : 0.f)
                           + (v.z != 0.f ? 1.f : 0.f) + (v.w != 0.f ? 1.f : 0.f));
            // prev element (index 4*lane-1) via DPP wave_shr:1 (0x138):
            // lane i <- lane i-1's v.w; lane 0 (invalid) keeps `old`:
            //   j==0 : old = own v.x  -> diff 0 (first element has no prev)
            //   j>0  : old = splat of lane63's v.w from chunk j-1 (readlane)
            int old;
            if (j == 0) old = __float_as_int(v.x);
            else        old = __builtin_amdgcn_readlane(__float_as_int(h[j-1].w), 63);
            float prev = __int_as_float(__builtin_amdgcn_update_dpp(
                old, __float_as_int(v.w), 0x138, 0xF, 0xF, false));
            cnt += (v.x != prev ? 1.f : 0.f) + (v.y != v.x ? 1.f : 0.f)
                 + (v.z != v.y ? 1.f : 0.f) + (v.w != v.z ? 1.f : 0.f);
        }

        // VALU-only wave reductions; results valid in lane 63
        d0 = wave_sum63(d0); d1 = wave_sum63(d1);
        d2 = wave_sum63(d2); d3 = wave_sum63(d3);
        tot = wave_sum63(tot); cnt = wave_sum63(cnt); mx = wave_max63(mx);

        float uq = floorf(cnt * (1.f / 4096.f));
        float pc = cnt - 4096.f * uq;

        float z0 = d0 + b0, z1 = d1 + b1, z2 = d2 + b2, z3 = d3 + b3;
        {
            float ux = fminf(fmaxf(u4.x, 1e-6f), 1.f - 1e-6f);
            float uy = fminf(fmaxf(u4.y, 1e-6f), 1.f - 1e-6f);
            float uz = fminf(fmaxf(u4.z, 1e-6f), 1.f - 1e-6f);
            float uw = fminf(fmaxf(u4.w, 1e-6f), 1.f - 1e-6f);
            z0 += -logf(-logf(ux));
            z1 += -logf(-logf(uy));
            z2 += -logf(-logf(uz));
            z3 += -logf(-logf(uw));
        }
        float m  = fmaxf(fmaxf(z0, z1), fmaxf(z2, z3));
        float p0 = expf(z0 - m), p1 = expf(z1 - m);
        float p2 = expf(z2 - m), p3 = expf(z3 - m);
        float inv = 1.f / (p0 + p1 + p2 + p3);
        float freq = mx / (tot + 1e-6f);
        float res = (p0 * tot + p1 * freq + p2 * uq + p3 * pc) * inv;
        if (lane == 63) out[row] = res;
    };

    // ---- 2-row ping-pong pipeline: prefetch B while computing A ----
    f32x4 hA[NITER], hB[NITER];
    f32x4 uA, uB;
    if (gw < N) loadrow(gw, hA, uA);
    for (int row = gw; row < N; row += 2 * GW) {
        const int rB  = row + GW;
        const int rA2 = row + 2 * GW;
        if (rB < N) loadrow(rB, hB, uB);   // prefetch B (overlaps compute A)
        compute(row, hA, uA);
        if (rA2 < N) loadrow(rA2, hA, uA); // prefetch next A (overlaps compute B)
        if (rB < N) compute(rB, hB, uB);
    }
}

extern "C" void kernel_launch(void* const* d_in, const int* in_sizes, int n_in,
                              void* d_out, int out_size, void* d_ws, size_t ws_size,
                              hipStream_t stream) {
    const float* hist = (const float*)d_in[0];  // [N, 2048]
    const float* W    = (const float*)d_in[1];  // [4, 2048]
    const float* b    = (const float*)d_in[2];  // [4]
    const float* gu   = (const float*)d_in[3];  // [N, 4]
    float* out = (float*)d_out;                 // [N]
    const int N = out_size;

    dim3 grid(1024), block(256);
    moe_fused_kernel<<<grid, block, 0, stream>>>(hist, W, b, gu, out, N);
}

// Round 6
// 181.861 us; speedup vs baseline: 1.0803x; 1.0803x over previous
//
#include <hip/hip_runtime.h>
#include <math.h>

// SparseExpertCountingNetwork: N=131072 rows, H=2048, E=4 experts.
// out[n] = sum_e softmax(hist[n]@W.T + b + gumbel(u[n]))_e * expert_e(hist[n])
// experts = [sum, max/(sum+1e-6), count(!=0), count(adjacent !=)]
//
// FINAL (= R4, best measured: 181.1 us = 5.94 TB/s, 92% of box fill BW).
// HBM-bound 1.074 GB hist stream. Design, each element HW-A/B-validated:
//  - one wave per row, W register-resident (128 VGPRs)      [R2: +?, R3 LDS regressed]
//  - 2-row ping-pong software pipeline                      [R2: 263->191 us]
//  - ZERO DS instructions: DPP reductions + readlane carry  [R4: 191->181 us]
//  - __builtin_nontemporal_load on the one-pass stream      [R5 A/B: NT 181 vs plain 196]

#define HDIM 2048
#define NITER 8  // HDIM / (64 lanes * 4 floats)

typedef float f32x4 __attribute__((ext_vector_type(4)));

// DPP full-wave reductions (VALU-only). After row_shr:1/2/4/8 + row_bcast:15
// + row_bcast:31, lane 63 holds the 64-lane result. (HW-validated R3/R4.)
#define DPP_ADD(x, ctrl)                                                     \
  (x) += __int_as_float(__builtin_amdgcn_update_dpp(                         \
      0, __float_as_int(x), (ctrl), 0xF, 0xF, false))
#define DPP_MAX(x, ctrl)                                                     \
  do {                                                                       \
    float _t = __int_as_float(__builtin_amdgcn_update_dpp(                   \
        __float_as_int(x), __float_as_int(x), (ctrl), 0xF, 0xF, false));     \
    (x) = fmaxf((x), _t);                                                    \
  } while (0)

__device__ __forceinline__ float wave_sum63(float x) {
  DPP_ADD(x, 0x111); DPP_ADD(x, 0x112); DPP_ADD(x, 0x114); DPP_ADD(x, 0x118);
  DPP_ADD(x, 0x142); DPP_ADD(x, 0x143);
  return x;  // valid in lane 63
}
__device__ __forceinline__ float wave_max63(float x) {
  DPP_MAX(x, 0x111); DPP_MAX(x, 0x112); DPP_MAX(x, 0x114); DPP_MAX(x, 0x118);
  DPP_MAX(x, 0x142); DPP_MAX(x, 0x143);
  return x;  // valid in lane 63
}

__global__ __launch_bounds__(256, 2) void moe_fused_kernel(
    const float* __restrict__ hist, const float* __restrict__ W,
    const float* __restrict__ bias, const float* __restrict__ gu,
    float* __restrict__ out, int N)
{
    const int lane = threadIdx.x & 63;
    const int wid  = threadIdx.x >> 6;
    const int gw   = blockIdx.x * 4 + wid;      // global wave id
    const int GW   = gridDim.x * 4;             // total waves
    const int cbase = 4 * lane;

    // W fragments in registers: w{e}[j] = W[e][256*j + 4*lane .. +3]
    f32x4 w0[NITER], w1[NITER], w2[NITER], w3[NITER];
#pragma unroll
    for (int j = 0; j < NITER; ++j) {
        int c = 256 * j + cbase;
        w0[j] = *(const f32x4*)(W + 0 * HDIM + c);
        w1[j] = *(const f32x4*)(W + 1 * HDIM + c);
        w2[j] = *(const f32x4*)(W + 2 * HDIM + c);
        w3[j] = *(const f32x4*)(W + 3 * HDIM + c);
    }
    const float b0 = bias[0], b1 = bias[1], b2 = bias[2], b3 = bias[3];

    // ---- row loader (nontemporal: hist is a one-pass 1 GB stream) ----
    auto loadrow = [&](int row, f32x4* h, f32x4& u) {
        const float* hr = hist + (size_t)row * HDIM;
#pragma unroll
        for (int j = 0; j < NITER; ++j)
            h[j] = __builtin_nontemporal_load((const f32x4*)(hr + 256 * j + cbase));
        u = *(const f32x4*)(gu + (size_t)row * 4);
    };

    // ---- per-row compute + store (no DS ops anywhere) ----
    auto compute = [&](int row, const f32x4* h, f32x4 u4) {
        float d0 = 0.f, d1 = 0.f, d2 = 0.f, d3 = 0.f;
        float tot = 0.f, mx = -3.4e38f, cnt = 0.f;  // cnt = uq*4096 + pc (exact)

#pragma unroll
        for (int j = 0; j < NITER; ++j) {
            f32x4 v = h[j];
            d0 += v.x * w0[j].x + v.y * w0[j].y + v.z * w0[j].z + v.w * w0[j].w;
            d1 += v.x * w1[j].x + v.y * w1[j].y + v.z * w1[j].z + v.w * w1[j].w;
            d2 += v.x * w2[j].x + v.y * w2[j].y + v.z * w2[j].z + v.w * w2[j].w;
            d3 += v.x * w3[j].x + v.y * w3[j].y + v.z * w3[j].z + v.w * w3[j].w;
            tot += (v.x + v.y) + (v.z + v.w);
            mx = fmaxf(mx, fmaxf(fmaxf(v.x, v.y), fmaxf(v.z, v.w)));
            cnt += 4096.f * ((v.x != 0.f ? 1.f : 0.f) + (v.y != 0.f ? 1.f : 0.f)
                           + (v.z != 0.f ? 1.f : 0.f) + (v.w != 0.f ? 1.f : 0.f));
            // prev element (index 4*lane-1) via DPP wave_shr:1 (0x138):
            // lane i <- lane i-1's v.w; lane 0 (invalid) keeps `old`:
            //   j==0 : old = own v.x  -> diff 0 (first element has no prev)
            //   j>0  : old = splat of lane63's v.w from chunk j-1 (readlane)
            int old;
            if (j == 0) old = __float_as_int(v.x);
            else        old = __builtin_amdgcn_readlane(__float_as_int(h[j-1].w), 63);
            float prev = __int_as_float(__builtin_amdgcn_update_dpp(
                old, __float_as_int(v.w), 0x138, 0xF, 0xF, false));
            cnt += (v.x != prev ? 1.f : 0.f) + (v.y != v.x ? 1.f : 0.f)
                 + (v.z != v.y ? 1.f : 0.f) + (v.w != v.z ? 1.f : 0.f);
        }

        // VALU-only wave reductions; results valid in lane 63
        d0 = wave_sum63(d0); d1 = wave_sum63(d1);
        d2 = wave_sum63(d2); d3 = wave_sum63(d3);
        tot = wave_sum63(tot); cnt = wave_sum63(cnt); mx = wave_max63(mx);

        float uq = floorf(cnt * (1.f / 4096.f));
        float pc = cnt - 4096.f * uq;

        float z0 = d0 + b0, z1 = d1 + b1, z2 = d2 + b2, z3 = d3 + b3;
        {
            float ux = fminf(fmaxf(u4.x, 1e-6f), 1.f - 1e-6f);
            float uy = fminf(fmaxf(u4.y, 1e-6f), 1.f - 1e-6f);
            float uz = fminf(fmaxf(u4.z, 1e-6f), 1.f - 1e-6f);
            float uw = fminf(fmaxf(u4.w, 1e-6f), 1.f - 1e-6f);
            z0 += -logf(-logf(ux));
            z1 += -logf(-logf(uy));
            z2 += -logf(-logf(uz));
            z3 += -logf(-logf(uw));
        }
        float m  = fmaxf(fmaxf(z0, z1), fmaxf(z2, z3));
        float p0 = expf(z0 - m), p1 = expf(z1 - m);
        float p2 = expf(z2 - m), p3 = expf(z3 - m);
        float inv = 1.f / (p0 + p1 + p2 + p3);
        float freq = mx / (tot + 1e-6f);
        float res = (p0 * tot + p1 * freq + p2 * uq + p3 * pc) * inv;
        if (lane == 63) out[row] = res;
    };

    // ---- 2-row ping-pong pipeline: prefetch B while computing A ----
    f32x4 hA[NITER], hB[NITER];
    f32x4 uA, uB;
    if (gw < N) loadrow(gw, hA, uA);
    for (int row = gw; row < N; row += 2 * GW) {
        const int rB  = row + GW;
        const int rA2 = row + 2 * GW;
        if (rB < N) loadrow(rB, hB, uB);   // prefetch B (overlaps compute A)
        compute(row, hA, uA);
        if (rA2 < N) loadrow(rA2, hA, uA); // prefetch next A (overlaps compute B)
        if (rB < N) compute(rB, hB, uB);
    }
}

extern "C" void kernel_launch(void* const* d_in, const int* in_sizes, int n_in,
                              void* d_out, int out_size, void* d_ws, size_t ws_size,
                              hipStream_t stream) {
    const float* hist = (const float*)d_in[0];  // [N, 2048]
    const float* W    = (const float*)d_in[1];  // [4, 2048]
    const float* b    = (const float*)d_in[2];  // [4]
    const float* gu   = (const float*)d_in[3];  // [N, 4]
    float* out = (float*)d_out;                 // [N]
    const int N = out_size;

    dim3 grid(1024), block(256);
    moe_fused_kernel<<<grid, block, 0, stream>>>(hist, W, b, gu, out, N);
}